// Round 1
// baseline (29.421 us; speedup 1.0000x reference)
//
#include <hip/hip_runtime.h>
#include <math.h>

// Problem: B=64, C=1, H=512, W=512 fp32.
// score[b] = cov(x1,x2) / sqrt((v1+eps)*(v2+eps)) per batch plane.
// One fused pass computing 5 moment sums; two-stage deterministic reduction.

#define HW          262144      // 512*512
#define PLANE_F4    65536       // HW/4
#define BPB         32          // blocks per batch
#define THREADS     256
#define F4_PER_THR  8           // PLANE_F4 / (BPB*THREADS)
#define NBATCH      64
#define EPSN        1e-5

__global__ __launch_bounds__(THREADS) void xcorr_partial(
        const float4* __restrict__ x1, const float4* __restrict__ x2,
        double* __restrict__ part) {
    const int b  = blockIdx.x / BPB;
    const int jb = blockIdx.x - b * BPB;
    const float4* p1 = x1 + (long long)b * PLANE_F4;
    const float4* p2 = x2 + (long long)b * PLANE_F4;
    const int base = jb * THREADS + threadIdx.x;   // 0..8191 within plane (f4 units)

    float s1 = 0.f, s2 = 0.f, s11 = 0.f, s22 = 0.f, s12 = 0.f;
    #pragma unroll
    for (int k = 0; k < F4_PER_THR; ++k) {
        const float4 a = p1[base + k * (BPB * THREADS)];
        const float4 c = p2[base + k * (BPB * THREADS)];
        s1  += (a.x + a.y) + (a.z + a.w);
        s2  += (c.x + c.y) + (c.z + c.w);
        s11 = fmaf(a.x, a.x, s11); s11 = fmaf(a.y, a.y, s11);
        s11 = fmaf(a.z, a.z, s11); s11 = fmaf(a.w, a.w, s11);
        s22 = fmaf(c.x, c.x, s22); s22 = fmaf(c.y, c.y, s22);
        s22 = fmaf(c.z, c.z, s22); s22 = fmaf(c.w, c.w, s22);
        s12 = fmaf(a.x, c.x, s12); s12 = fmaf(a.y, c.y, s12);
        s12 = fmaf(a.z, c.z, s12); s12 = fmaf(a.w, c.w, s12);
    }

    // promote to double, reduce across the block (deterministic tree)
    double d0 = s1, d1 = s2, d2 = s11, d3 = s22, d4 = s12;
    #pragma unroll
    for (int off = 32; off > 0; off >>= 1) {
        d0 += __shfl_down(d0, off, 64);
        d1 += __shfl_down(d1, off, 64);
        d2 += __shfl_down(d2, off, 64);
        d3 += __shfl_down(d3, off, 64);
        d4 += __shfl_down(d4, off, 64);
    }
    __shared__ double lds[4][5];
    const int lane = threadIdx.x & 63;
    const int wv   = threadIdx.x >> 6;
    if (lane == 0) {
        lds[wv][0] = d0; lds[wv][1] = d1; lds[wv][2] = d2;
        lds[wv][3] = d3; lds[wv][4] = d4;
    }
    __syncthreads();
    if (threadIdx.x == 0) {
        double* o = part + (long long)blockIdx.x * 5;
        #pragma unroll
        for (int i = 0; i < 5; ++i)
            o[i] = (lds[0][i] + lds[1][i]) + (lds[2][i] + lds[3][i]);
    }
}

__global__ __launch_bounds__(64) void xcorr_final(
        const double* __restrict__ part, float* __restrict__ out) {
    const int b = threadIdx.x;            // one thread per batch, 64 threads
    const double* p = part + (long long)b * BPB * 5;
    double s1 = 0, s2 = 0, s11 = 0, s22 = 0, s12 = 0;
    #pragma unroll
    for (int j = 0; j < BPB; ++j) {       // fixed order: deterministic
        s1  += p[j * 5 + 0];
        s2  += p[j * 5 + 1];
        s11 += p[j * 5 + 2];
        s22 += p[j * 5 + 3];
        s12 += p[j * 5 + 4];
    }
    const double N  = (double)HW;
    const double m1 = s1 / N, m2 = s2 / N;
    const double v1 = s11 / N - m1 * m1;
    const double v2 = s22 / N - m2 * m2;
    const double cv = s12 / N - m1 * m2;
    out[b] = (float)(cv / sqrt((v1 + EPSN) * (v2 + EPSN)));
}

extern "C" void kernel_launch(void* const* d_in, const int* in_sizes, int n_in,
                              void* d_out, int out_size, void* d_ws, size_t ws_size,
                              hipStream_t stream) {
    const float4* x1 = (const float4*)d_in[0];
    const float4* x2 = (const float4*)d_in[1];
    double* part = (double*)d_ws;          // NBATCH*BPB*5 doubles = 80 KiB
    float* out = (float*)d_out;

    xcorr_partial<<<NBATCH * BPB, THREADS, 0, stream>>>(x1, x2, part);
    xcorr_final<<<1, 64, 0, stream>>>(part, out);
}

// Round 2
// 28.135 us; speedup vs baseline: 1.0457x; 1.0457x over previous
//
#include <hip/hip_runtime.h>
#include <math.h>

// B=64, C=1, H=512, W=512 fp32.
// score[b] = cov(x1,x2) / sqrt((v1+eps)*(v2+eps)) per batch plane.
// Stage 1: 2048 blocks x 256 thr, 8 independent float4 loads in flight,
//          per-thread fp32 fma accum, double tree reduce -> 5 doubles/block.
// Stage 2: one 256-thread block, 4 lanes per batch, deterministic tree.

#define HW        262144      // 512*512
#define PLANE_F4  65536       // HW/4
#define BPB       32          // blocks per batch plane
#define THREADS   256
#define STRIDE    (BPB * THREADS)   // 8192 float4s
#define NBATCH    64
#define EPSN      1e-5

#define ACC(a, c)                                                     \
    s1  += (a.x + a.y) + (a.z + a.w);                                 \
    s2  += (c.x + c.y) + (c.z + c.w);                                 \
    s11 = fmaf(a.x, a.x, s11); s11 = fmaf(a.y, a.y, s11);             \
    s11 = fmaf(a.z, a.z, s11); s11 = fmaf(a.w, a.w, s11);             \
    s22 = fmaf(c.x, c.x, s22); s22 = fmaf(c.y, c.y, s22);             \
    s22 = fmaf(c.z, c.z, s22); s22 = fmaf(c.w, c.w, s22);             \
    s12 = fmaf(a.x, c.x, s12); s12 = fmaf(a.y, c.y, s12);             \
    s12 = fmaf(a.z, c.z, s12); s12 = fmaf(a.w, c.w, s12);

__global__ __launch_bounds__(THREADS, 8) void xcorr_partial(
        const float4* __restrict__ x1, const float4* __restrict__ x2,
        double* __restrict__ part) {
    const int b  = blockIdx.x >> 5;          // / BPB
    const int jb = blockIdx.x & (BPB - 1);
    const int base = jb * THREADS + threadIdx.x;
    const float4* q1 = x1 + (long long)b * PLANE_F4 + base;
    const float4* q2 = x2 + (long long)b * PLANE_F4 + base;

    float s1 = 0.f, s2 = 0.f, s11 = 0.f, s22 = 0.f, s12 = 0.f;

    // ---- batch 0: 8 independent 16B loads issued before any FMA ----
    {
        const float4 a0 = q1[0 * STRIDE];
        const float4 a1 = q1[1 * STRIDE];
        const float4 a2 = q1[2 * STRIDE];
        const float4 a3 = q1[3 * STRIDE];
        const float4 c0 = q2[0 * STRIDE];
        const float4 c1 = q2[1 * STRIDE];
        const float4 c2 = q2[2 * STRIDE];
        const float4 c3 = q2[3 * STRIDE];
        ACC(a0, c0) ACC(a1, c1) ACC(a2, c2) ACC(a3, c3)
    }
    // ---- batch 1 ----
    {
        const float4 a0 = q1[4 * STRIDE];
        const float4 a1 = q1[5 * STRIDE];
        const float4 a2 = q1[6 * STRIDE];
        const float4 a3 = q1[7 * STRIDE];
        const float4 c0 = q2[4 * STRIDE];
        const float4 c1 = q2[5 * STRIDE];
        const float4 c2 = q2[6 * STRIDE];
        const float4 c3 = q2[7 * STRIDE];
        ACC(a0, c0) ACC(a1, c1) ACC(a2, c2) ACC(a3, c3)
    }

    // promote to double, wave butterfly then LDS cross-wave (deterministic)
    double d0 = s1, d1 = s2, d2 = s11, d3 = s22, d4 = s12;
    #pragma unroll
    for (int off = 32; off > 0; off >>= 1) {
        d0 += __shfl_down(d0, off, 64);
        d1 += __shfl_down(d1, off, 64);
        d2 += __shfl_down(d2, off, 64);
        d3 += __shfl_down(d3, off, 64);
        d4 += __shfl_down(d4, off, 64);
    }
    __shared__ double lds[4][5];
    const int lane = threadIdx.x & 63;
    const int wv   = threadIdx.x >> 6;
    if (lane == 0) {
        lds[wv][0] = d0; lds[wv][1] = d1; lds[wv][2] = d2;
        lds[wv][3] = d3; lds[wv][4] = d4;
    }
    __syncthreads();
    if (threadIdx.x == 0) {
        double* o = part + (long long)blockIdx.x * 5;
        #pragma unroll
        for (int i = 0; i < 5; ++i)
            o[i] = (lds[0][i] + lds[1][i]) + (lds[2][i] + lds[3][i]);
    }
}

__global__ __launch_bounds__(256) void xcorr_final(
        const double* __restrict__ part, float* __restrict__ out) {
    const int tid = threadIdx.x;
    const int b = tid >> 2;               // batch 0..63
    const int g = tid & 3;                // 4 lanes per batch
    const double* p = part + (long long)b * BPB * 5 + (long long)g * 8 * 5;
    double s0 = 0, s1 = 0, s2 = 0, s3 = 0, s4 = 0;
    #pragma unroll
    for (int j = 0; j < 8; ++j) {         // fixed order: deterministic
        s0 += p[j * 5 + 0];
        s1 += p[j * 5 + 1];
        s2 += p[j * 5 + 2];
        s3 += p[j * 5 + 3];
        s4 += p[j * 5 + 4];
    }
    // reduce across the 4 lanes of this batch group (aligned within a wave)
    #pragma unroll
    for (int off = 2; off > 0; off >>= 1) {
        s0 += __shfl_down(s0, off, 64);
        s1 += __shfl_down(s1, off, 64);
        s2 += __shfl_down(s2, off, 64);
        s3 += __shfl_down(s3, off, 64);
        s4 += __shfl_down(s4, off, 64);
    }
    if (g == 0) {
        const double N  = (double)HW;
        const double m1 = s0 / N, m2 = s1 / N;
        const double v1 = s2 / N - m1 * m1;
        const double v2 = s3 / N - m2 * m2;
        const double cv = s4 / N - m1 * m2;
        out[b] = (float)(cv / sqrt((v1 + EPSN) * (v2 + EPSN)));
    }
}

extern "C" void kernel_launch(void* const* d_in, const int* in_sizes, int n_in,
                              void* d_out, int out_size, void* d_ws, size_t ws_size,
                              hipStream_t stream) {
    const float4* x1 = (const float4*)d_in[0];
    const float4* x2 = (const float4*)d_in[1];
    double* part = (double*)d_ws;          // NBATCH*BPB*5 doubles = 80 KiB
    float* out = (float*)d_out;

    xcorr_partial<<<NBATCH * BPB, THREADS, 0, stream>>>(x1, x2, part);
    xcorr_final<<<1, 256, 0, stream>>>(part, out);
}